// Round 6
// baseline (7049.586 us; speedup 1.0000x reference)
//
#include <hip/hip_runtime.h>

#define TMAX 8192
#define H 128

__device__ __forceinline__ float sigf(float x)       { return 1.f / (1.f + __expf(-x)); }
__device__ __forceinline__ float tanhf_fast(float x) { return 2.f / (1.f + __expf(-2.f * x)) - 1.f; }

// VALU-pipe cross-lane move (DPP), avoids the DS pipe entirely.
template<int CTRL>
__device__ __forceinline__ float dppmove(float v) {
    return __int_as_float(__builtin_amdgcn_update_dpp(
        0, __float_as_int(v), CTRL, 0xf, 0xf, true));
}

// 512 threads, 8 waves (2/SIMD). Lane l: g = l&7 (k-group), j = wave*8 + (l>>3).
// Lane owns 8 rows {j+64m} x 16 k (128 weight VGPRs). Lane g reads h[16g:16g+16)
// (r5 BUG: read 16*(g&3) -> lanes 4..7 used the wrong h half). Reduction across
// g via DPP butterfly (VALU, not LDS). Gate quads complete in-wave ->
// distributed masked activation, ONE barrier/step, double-buffered h.
__global__ __launch_bounds__(512)
__attribute__((amdgpu_waves_per_eu(2, 2)))
void lstm_seq_kernel(const float* __restrict__ x,
                     const float* __restrict__ Wih,
                     const float* __restrict__ Whh,
                     const float* __restrict__ bih,
                     const float* __restrict__ bhh,
                     const float* __restrict__ Wlin,
                     const float* __restrict__ blin,
                     const float* __restrict__ h0,
                     const float* __restrict__ c0,
                     float* __restrict__ out,
                     int T)
{
    __shared__ float x_s[TMAX];          // 32 KB
    __shared__ float hbuf[2][H];         // double-buffered h (1 KB)

    const int t  = threadIdx.x;          // 0..511
    const int w  = t >> 6;               // wave 0..7
    const int l  = t & 63;
    const int g  = l & 7;                // k-group: k in [16g, 16g+16)
    const int jl = l >> 3;               // 0..7
    const int j  = w * 8 + jl;           // 0..63

    // Stage input sequence into LDS (one-time, coalesced).
    for (int i = t; i < T; i += 512) x_s[i] = x[i];

    // Weights: 8 rows (j + 64m) x 16 k  -> 32 float4 = 128 VGPRs.
    float4 wv[32];
    #pragma unroll
    for (int m = 0; m < 8; ++m) {
        const float4* src = (const float4*)(Whh + (j + 64 * m) * H + 16 * g);
        #pragma unroll
        for (int i = 0; i < 4; ++i) wv[m * 4 + i] = src[i];
    }
    // Pin: volatile asm consumes+redefines so loads can't be sunk into the loop.
    #pragma unroll
    for (int m = 0; m < 32; ++m)
        asm volatile("" : "+v"(wv[m].x), "+v"(wv[m].y), "+v"(wv[m].z), "+v"(wv[m].w));

    // Activation-lane (g<2) state: output index jj, cell c, x-weights, biases.
    const int jj = j + 64 * g;           // only meaningful for g<2 (0..127)
    float c = 0.f;
    float wih[4], bs[4];
    if (g < 2) {
        c = c0[jj];
        #pragma unroll
        for (int m = 0; m < 4; ++m) {
            wih[m] = Wih[jj + 128 * m];
            bs[m]  = bih[jj + 128 * m] + bhh[jj + 128 * m];
        }
    }
    if (t < H) hbuf[0][t] = h0[t];
    __syncthreads();

    const int hoff = 16 * g;             // this lane's k-slice of h

    for (int step = 0; step < T; ++step) {
        const int b = step & 1;
        const float4* hp = (const float4*)&hbuf[b][hoff];
        const float4 h0v = hp[0], h1v = hp[1], h2v = hp[2], h3v = hp[3];

        float acc[8];
        #pragma unroll
        for (int m = 0; m < 8; ++m) {
            const float4 wa = wv[m * 4 + 0];
            const float4 wb = wv[m * 4 + 1];
            const float4 wc = wv[m * 4 + 2];
            const float4 wd = wv[m * 4 + 3];
            float s = 0.f;
            s = fmaf(wa.x, h0v.x, s); s = fmaf(wa.y, h0v.y, s);
            s = fmaf(wa.z, h0v.z, s); s = fmaf(wa.w, h0v.w, s);
            s = fmaf(wb.x, h1v.x, s); s = fmaf(wb.y, h1v.y, s);
            s = fmaf(wb.z, h1v.z, s); s = fmaf(wb.w, h1v.w, s);
            s = fmaf(wc.x, h2v.x, s); s = fmaf(wc.y, h2v.y, s);
            s = fmaf(wc.z, h2v.z, s); s = fmaf(wc.w, h2v.w, s);
            s = fmaf(wd.x, h3v.x, s); s = fmaf(wd.y, h3v.y, s);
            s = fmaf(wd.z, h3v.z, s); s = fmaf(wd.w, h3v.w, s);
            acc[m] = s;
        }

        // DPP butterfly across the 8 k-groups (lanes g=0..7 within each octet):
        // xor1 (quad_perm [1,0,3,2]), xor2 (quad_perm [2,3,0,1]), then
        // row_half_mirror (g -> 7-g; quads hold uniform values by then, so it
        // completes the octet sum). All lanes end with the full dot products.
        #pragma unroll
        for (int m = 0; m < 8; ++m) {
            acc[m] += dppmove<0xB1>(acc[m]);
            acc[m] += dppmove<0x4E>(acc[m]);
            acc[m] += dppmove<0x141>(acc[m]);
        }

        if (g < 2) {
            const bool odd = (g == 1);
            float gi = odd ? acc[1] : acc[0];
            float gf = odd ? acc[3] : acc[2];
            float gg = odd ? acc[5] : acc[4];
            float go = odd ? acc[7] : acc[6];
            const float xv = x_s[step];
            gi += fmaf(xv, wih[0], bs[0]);
            gf += fmaf(xv, wih[1], bs[1]);
            gg += fmaf(xv, wih[2], bs[2]);
            go += fmaf(xv, wih[3], bs[3]);
            const float ig = sigf(gi);
            const float fg = sigf(gf);
            const float gt = tanhf_fast(gg);
            const float og = sigf(go);
            c = fmaf(fg, c, ig * gt);
            hbuf[b ^ 1][jj] = og * tanhf_fast(c);
        }
        __syncthreads();   // single barrier: separates h-writes from next reads
    }

    // Final linear: out = dot(W_lin, h_T) + b_lin  (wave 0 only)
    if (t < 64) {
        const float* hs = hbuf[T & 1];
        float v = Wlin[t] * hs[t] + Wlin[t + 64] * hs[t + 64];
        #pragma unroll
        for (int off = 32; off >= 1; off >>= 1) v += __shfl_down(v, off);
        if (t == 0) out[0] = v + blin[0];
    }
}

extern "C" void kernel_launch(void* const* d_in, const int* in_sizes, int n_in,
                              void* d_out, int out_size, void* d_ws, size_t ws_size,
                              hipStream_t stream) {
    const float* x    = (const float*)d_in[0];
    const float* Wih  = (const float*)d_in[1];
    const float* Whh  = (const float*)d_in[2];
    const float* bih  = (const float*)d_in[3];
    const float* bhh  = (const float*)d_in[4];
    const float* Wlin = (const float*)d_in[5];
    const float* blin = (const float*)d_in[6];
    const float* h0   = (const float*)d_in[7];
    const float* c0   = (const float*)d_in[8];
    float* out = (float*)d_out;
    const int T = in_sizes[0];

    lstm_seq_kernel<<<1, 512, 0, stream>>>(x, Wih, Whh, bih, bhh, Wlin, blin,
                                           h0, c0, out, T);
}